// Round 1
// baseline (413.725 us; speedup 1.0000x reference)
//
#include <hip/hip_runtime.h>
#include <stdint.h>

// QuantizedLinear: B=4, S=2048, IN=4096, OUT=4096, OUTLIER=128
// Unified int8 path:
//   W8[o,i] = round(w[o, invp[i]] / w_s_o),  w[o,:] = [qw*alpha | fpw] permuted
//   w_s_o   = rowabsmax(w[o,:]) / 127        (per-output-row scale)
//   A8[m,i] = round(A[m,i] / s_m),  s_m = rowabsmax / 127
//   out[m,o] = s_m * w_s_o * (A8 . W8^T)[m,o] + bias[o]
#define IN_F  4096
#define OUT_F 4096
#define OUTL  128
#define QIN   (IN_F - OUTL)   // 3968
#define MTOT  8192            // B*S
#define BM 256
#define BN 256
#define BKB 128               // K-bytes per LDS row per K-tile
#define NKT (IN_F / BKB)      // 32 K-tiles

typedef unsigned short u16;
typedef int i32x4 __attribute__((ext_vector_type(4)));

// ---------------------------------------------------------------------------
// Fused prep. Blocks [0, OUT_F): weight rows. Blocks [OUT_F, OUT_F+MTOT):
// activation rows. All global reads coalesced float4; stores coalesced 16B.
// Weight gather LDS is PADDED (addr = j + (j>>4)): unpadded, lane l of the
// gather hits bank (16l)%32 -> 32-way conflict; pad makes lane stride 17
// (coprime with 32) -> conflict-free.
// ---------------------------------------------------------------------------
__global__ __launch_bounds__(256) void prep_fused(
    const float* __restrict__ A, signed char* __restrict__ A8,
    float* __restrict__ s_arr,
    const float* __restrict__ qw, const float* __restrict__ fpw,
    const float* __restrict__ alpha, const int* __restrict__ invp,
    signed char* __restrict__ W8, float* __restrict__ t_arr) {
  const int tid = threadIdx.x;
  __shared__ float red[4];

  if (blockIdx.x >= OUT_F) {
    // ---- activation row: absmax -> s_m, quantize to int8 ----
    const int m = blockIdx.x - OUT_F;
    const float* row = A + (size_t)m * IN_F;
    float4 v[4];
    float amax = 0.f;
#pragma unroll
    for (int k = 0; k < 4; ++k) {
      v[k] = ((const float4*)row)[k * 256 + tid];
      amax = fmaxf(amax, fmaxf(fmaxf(fabsf(v[k].x), fabsf(v[k].y)),
                               fmaxf(fabsf(v[k].z), fabsf(v[k].w))));
    }
#pragma unroll
    for (int off = 32; off; off >>= 1)
      amax = fmaxf(amax, __shfl_xor(amax, off, 64));
    if ((tid & 63) == 0) red[tid >> 6] = amax;
    __syncthreads();
    amax = fmaxf(fmaxf(red[0], red[1]), fmaxf(red[2], red[3]));
    const float inv = 127.f / amax;
    if (tid == 0) s_arr[m] = amax / 127.f;
#pragma unroll
    for (int k = 0; k < 4; ++k) {
      const int q0 = __float2int_rn(v[k].x * inv);
      const int q1 = __float2int_rn(v[k].y * inv);
      const int q2 = __float2int_rn(v[k].z * inv);
      const int q3 = __float2int_rn(v[k].w * inv);
      const uint32_t p = (q0 & 255) | ((q1 & 255) << 8) |
                         ((q2 & 255) << 16) | ((uint32_t)(q3 & 255) << 24);
      ((uint32_t*)A8)[(size_t)m * (IN_F / 4) + k * 256 + tid] = p;
    }
  } else {
    // ---- weight row: stage qw/fpw in LDS (padded), rowabsmax of
    //      [qw*a | fpw], permuted gather, quantize to int8 ----
    const int o = blockIdx.x;
    __shared__ float qs[QIN + (QIN >> 4)];  // 4216 floats, padded layout
    __shared__ float fs[OUTL];
    const float a = alpha[o];
    float amax = 0.f;
    const float4* qrow = (const float4*)(qw + (size_t)o * QIN);
#pragma unroll
    for (int k = 0; k < 4; ++k) {
      const int idx = k * 256 + tid;
      if (idx < QIN / 4) {
        const float4 q = qrow[idx];
        // padded addr of j=4*idx is 4*idx + (idx>>2); all 4 elems stay in
        // the same 16-float pad block (4*idx % 16 in {0,4,8,12}).
        const int b0 = idx * 4 + (idx >> 2);
        qs[b0]     = q.x;
        qs[b0 + 1] = q.y;
        qs[b0 + 2] = q.z;
        qs[b0 + 3] = q.w;
        const float qm = fmaxf(fmaxf(fabsf(q.x), fabsf(q.y)),
                               fmaxf(fabsf(q.z), fabsf(q.w)));
        amax = fmaxf(amax, qm * a);
      }
    }
    if (tid < OUTL / 4) {
      const float4 f = ((const float4*)(fpw + (size_t)o * OUTL))[tid];
      ((float4*)fs)[tid] = f;
      amax = fmaxf(amax, fmaxf(fmaxf(fabsf(f.x), fabsf(f.y)),
                               fmaxf(fabsf(f.z), fabsf(f.w))));
    }
#pragma unroll
    for (int off = 32; off; off >>= 1)
      amax = fmaxf(amax, __shfl_xor(amax, off, 64));
    if ((tid & 63) == 0) red[tid >> 6] = amax;
    __syncthreads();  // also covers qs/fs visibility
    amax = fmaxf(fmaxf(red[0], red[1]), fmaxf(red[2], red[3]));
    const float invws = 127.f / amax;
    if (tid == 0) t_arr[o] = amax / 127.f;

    signed char vals[16];
#pragma unroll
    for (int q = 0; q < 4; ++q) {
      const int4 jj = ((const int4*)invp)[tid * 4 + q];
      const int j[4] = {jj.x, jj.y, jj.z, jj.w};
#pragma unroll
      for (int e = 0; e < 4; ++e) {
        const int je = j[e];
        const float v = (je < QIN) ? qs[je + (je >> 4)] * a : fs[je - QIN];
        vals[q * 4 + e] = (signed char)__float2int_rn(v * invws);
      }
    }
    ((uint4*)(W8 + (size_t)o * IN_F))[tid] = *(const uint4*)vals;
  }
}

// ---------------------------------------------------------------------------
// GEMM: 256x256 tile, 8 waves (2M x 4N), K-tile = 128 B, double-buffered LDS
// (128 KB), counted-vmcnt pipeline (T3+T4) + setprio (T5).
//
// Per K-tile: issue 8 global_load_lds for tile kt+1 into buf^1, then
// s_waitcnt vmcnt(8)  -> waits ONLY for tile kt's 8 loads (issued last iter),
// the 8 just-issued stay in flight across the barrier and land under this
// tile's 64 MFMAs. Raw s_barrier (NOT __syncthreads, which emits vmcnt(0)
// and drains the pipeline). asm memory clobbers adjacent to each barrier
// stop the compiler from moving LDS reads / GLDS across the sync points.
//
// Hazards:
//  - read buf[cur] before writes land: vmcnt(8) confirms my tile-kt loads,
//    barrier confirms everyone's -> safe.
//  - overwrite buf[cur] (iter kt+1 stages into buf[cur]): my ds_reads are
//    complete at lgkmcnt(0), barrier orders all waves' reads before any
//    wave's next STAGE -> safe.
//
// LDS layout (unchanged, measured 0 bank conflicts): row r holds 8 x 16B
// chunks; slot s stores global chunk s^(r&7), achieved by pre-swizzling the
// per-lane GLOBAL address (GLDS LDS dest must stay linear).
// ---------------------------------------------------------------------------
#define GLDS(g, l)                                                              \
  __builtin_amdgcn_global_load_lds(                                             \
      (const __attribute__((address_space(1))) void*)(g),                       \
      (__attribute__((address_space(3))) void*)(l), 16, 0, 0)

__global__ __launch_bounds__(512, 2) void gemm_i8(
    const signed char* __restrict__ A8, const signed char* __restrict__ W8,
    const float* __restrict__ s_arr, const float* __restrict__ t_arr,
    const float* __restrict__ bias, float* __restrict__ C) {
  __shared__ unsigned char As8[2][BM * BKB];  // 2 x 32 KB
  __shared__ unsigned char Bs8[2][BN * BKB];  // 2 x 32 KB  -> 128 KB total

  const int tid  = threadIdx.x;
  const int wave = tid >> 6;   // 0..7
  const int lane = tid & 63;

  // XCD-aware swizzle: 512 blocks, 512 % 8 == 0 -> bijective. Each XCD gets
  // 64 consecutive swizzled ids = 4 bm-rows x all 16 bn -> A-panel L2 reuse.
  const int bid = ((blockIdx.x & 7) << 6) | ((int)blockIdx.x >> 3);
  const int bm = bid >> 4;   // 0..31
  const int bn = bid & 15;   // 0..15

  const int wm = (wave >> 2) * 128;  // 0 / 128
  const int wn = (wave & 3) * 64;    // 0 / 64 / 128 / 192

  // Staging: wave w covers rows [w*32, w*32+32) of both tiles, 4 GLDS each
  // (8 rows x 128 B = 1 KB per GLDS). Lane l -> row (l>>3), slot (l&7);
  // global chunk pre-swizzled so slot s of row r holds chunk s^(r&7).
  const int srow   = wave * 32 + (lane >> 3);
  const int schunk = (lane & 7) ^ ((lane >> 3) & 7);
  const signed char* Ag = A8 + (size_t)(bm * BM + srow) * IN_F + schunk * 16;
  const signed char* Wg = W8 + (size_t)(bn * BN + srow) * IN_F + schunk * 16;
  const int sdst = wave * 32 * BKB;

  i32x4 acc[8][4];
#pragma unroll
  for (int mi = 0; mi < 8; ++mi)
#pragma unroll
    for (int ni = 0; ni < 4; ++ni) acc[mi][ni] = (i32x4){0, 0, 0, 0};

  const int fr = lane & 15;  // fragment row (m for A, n for B)
  const int fq = lane >> 4;  // quad -> 16B k-chunk within 64B k-step

  // Precomputed fragment LDS byte offsets (within one buffer).
  int aoff[8], boff[4], ck[2];
  ck[0] = ((0 + fq) ^ (fr & 7)) * 16;
  ck[1] = ((4 + fq) ^ (fr & 7)) * 16;
#pragma unroll
  for (int mi = 0; mi < 8; ++mi) aoff[mi] = (wm + mi * 16 + fr) * BKB;
#pragma unroll
  for (int ni = 0; ni < 4; ++ni) boff[ni] = (wn + ni * 16 + fr) * BKB;

  auto STAGE = [&](int buf, int kt) {
#pragma unroll
    for (int t = 0; t < 4; ++t) {
      GLDS(Ag + (size_t)kt * BKB + t * 8 * IN_F, &As8[buf][sdst + t * 8 * BKB]);
      GLDS(Wg + (size_t)kt * BKB + t * 8 * IN_F, &Bs8[buf][sdst + t * 8 * BKB]);
    }
  };

  auto COMPUTE = [&](int buf) {
#pragma unroll
    for (int ks = 0; ks < 2; ++ks) {
      i32x4 bg[4], af[8];
#pragma unroll
      for (int ni = 0; ni < 4; ++ni)
        bg[ni] = *(const i32x4*)&Bs8[buf][boff[ni] + ck[ks]];
#pragma unroll
      for (int mi = 0; mi < 8; ++mi)
        af[mi] = *(const i32x4*)&As8[buf][aoff[mi] + ck[ks]];
      __builtin_amdgcn_s_setprio(1);
#pragma unroll
      for (int mi = 0; mi < 8; ++mi)
#pragma unroll
        for (int ni = 0; ni < 4; ++ni)
          acc[mi][ni] = __builtin_amdgcn_mfma_i32_16x16x64_i8(
              af[mi], bg[ni], acc[mi][ni], 0, 0, 0);
      __builtin_amdgcn_s_setprio(0);
    }
  };

  STAGE(0, 0);  // prologue: tile 0 -> buf0 (8 loads in flight)

  for (int kt = 0; kt < NKT - 1; ++kt) {
    STAGE((kt & 1) ^ 1, kt + 1);                     // tile kt+1 -> other buf
    asm volatile("s_waitcnt vmcnt(8)" ::: "memory"); // tile kt landed (mine)
    __builtin_amdgcn_s_barrier();                    // landed for all waves
    COMPUTE(kt & 1);
    asm volatile("s_waitcnt lgkmcnt(0)" ::: "memory"); // my ds_reads done
    __builtin_amdgcn_s_barrier();                    // all reads done -> next
  }
  asm volatile("s_waitcnt vmcnt(0)" ::: "memory");   // drain last tile
  __builtin_amdgcn_s_barrier();
  COMPUTE((NKT - 1) & 1);

  // Epilogue: C/D layout col = lane&15 (n), row = (lane>>4)*4 + reg (m).
  float sv[8][4];
#pragma unroll
  for (int mi = 0; mi < 8; ++mi)
#pragma unroll
    for (int rr = 0; rr < 4; ++rr)
      sv[mi][rr] = s_arr[bm * BM + wm + mi * 16 + fq * 4 + rr];

#pragma unroll
  for (int ni = 0; ni < 4; ++ni) {
    const int n = bn * BN + wn + ni * 16 + fr;
    const float tn = t_arr[n];
    const float bv = bias[n];
#pragma unroll
    for (int mi = 0; mi < 8; ++mi) {
      const int m0 = bm * BM + wm + mi * 16 + fq * 4;
#pragma unroll
      for (int rr = 0; rr < 4; ++rr)
        C[(size_t)(m0 + rr) * OUT_F + n] =
            (float)acc[mi][ni][rr] * (sv[mi][rr] * tn) + bv;
    }
  }
}

extern "C" void kernel_launch(void* const* d_in, const int* in_sizes, int n_in,
                              void* d_out, int out_size, void* d_ws, size_t ws_size,
                              hipStream_t stream) {
  const float* input = (const float*)d_in[0];  // (4,2048,4096) fp32
  const float* qw    = (const float*)d_in[1];  // (4096,3968) fp32
  const float* fpw   = (const float*)d_in[2];  // (4096,128) fp32
  const float* alpha = (const float*)d_in[3];  // (4096,1) fp32
  const float* bias  = (const float*)d_in[4];  // (4096,) fp32
  const int*   invp  = (const int*)d_in[5];    // (4096,) int32

  char* ws = (char*)d_ws;
  signed char* A8    = (signed char*)ws;                        // 32 MB
  signed char* W8    = (signed char*)(ws + (32ull << 20));      // 16 MB
  float* s_arr = (float*)(ws + (48ull << 20));                  // 32 KB
  float* t_arr = (float*)(ws + (48ull << 20) + (64ull << 10));  // 16 KB
  float* out = (float*)d_out;

  prep_fused<<<OUT_F + MTOT, 256, 0, stream>>>(input, A8, s_arr, qw, fpw,
                                               alpha, invp, W8, t_arr);

  gemm_i8<<<dim3((MTOT / BM) * (OUT_F / BN)), dim3(512), 0, stream>>>(
      A8, W8, s_arr, t_arr, bias, out);
}